// Round 16
// baseline (247.768 us; speedup 1.0000x reference)
//
#include <hip/hip_runtime.h>

#define CC 19
#define NPOS 361
#define NPAD 384
#define DIM 256
#define TKEY 32
#define NTILES 12

// attn LDS layout (bytes), 128-thread block (2 waves):
//   [0, 32768)      : 2 x-buffers, each 32 rows x 512 B (XOR-swizzled via
//                     pre-swizzled global source; rotation t%2)
//   [32768, 34304)  : mask table 32 q x 12 tiles u32
//   [34304, 34560)  : sL (2 waves x 32 floats)
// 34816 x 4 blocks = 139264 <= 160 KiB -> 4 blocks/CU co-resident: same
// 8 waves/CU as R13, but 4 independent barrier domains of 2 waves instead
// of 2 domains of 4 -- finer decorrelation (the R1->R2 win mechanism).
#define LDS_BYTES 34816

using bf16x8 = __attribute__((ext_vector_type(8))) short;
using f16x4  = __attribute__((ext_vector_type(4))) _Float16;
using floatx4 = __attribute__((ext_vector_type(4))) float;
using uintx2 = __attribute__((ext_vector_type(2))) unsigned int;

__device__ __forceinline__ unsigned short f2bf(float f) {
  unsigned u = __builtin_bit_cast(unsigned, f);
  u += 0x7fffu + ((u >> 16) & 1u);
  return (unsigned short)(u >> 16);
}

__device__ __forceinline__ f16x4 pack4h(float a, float b, float c2, float d) {
  const auto h01 = __builtin_amdgcn_cvt_pkrtz(a, b);
  const auto h23 = __builtin_amdgcn_cvt_pkrtz(c2, d);
  uintx2 uv = {__builtin_bit_cast(unsigned, h01), __builtin_bit_cast(unsigned, h23)};
  return __builtin_bit_cast(f16x4, uv);
}

// direct global->LDS DMA, 16 B per lane (HW: lds dest = wave-uniform base + lane*16)
__device__ __forceinline__ void gload_lds16(const void* g, void* l) {
  __builtin_amdgcn_global_load_lds(
      (const __attribute__((address_space(1))) void*)g,
      (__attribute__((address_space(3))) void*)l, 16, 0, 0);
}

// fused conversion: x (zero-padded 361->384 rows) + all weights, f32 -> bf16
__global__ void conv_all_kernel(const float* __restrict__ x,
                                const float* __restrict__ w_in,
                                const float* __restrict__ w_out,
                                const float* __restrict__ w_fuse,
                                unsigned short* __restrict__ ws) {
  const int j = blockIdx.x * 256 + threadIdx.x;
  float4 v = make_float4(0.f, 0.f, 0.f, 0.f);
  unsigned short* dst;
  if (j < 786432) {
    const int row = j >> 6;
    const int off = (j & 63) << 2;
    const int b = row / NPAD;
    const int r = row - b * NPAD;
    if (r < NPOS) v = *(const float4*)&x[(b * NPOS + r) * DIM + off];
    dst = &ws[row * DIM + off];
  } else if (j < 1720320) {
    const int k = j - 786432;
    v = *(const float4*)&w_in[k << 2];
    dst = &ws[3145728 + (k << 2)];
  } else if (j < 2031616) {
    const int k = j - 1720320;
    v = *(const float4*)&w_out[k << 2];
    dst = &ws[6881280 + (k << 2)];
  } else {
    const int k = j - 2031616;
    v = *(const float4*)&w_fuse[k << 2];
    dst = &ws[8126464 + (k << 2)];
  }
  ushort4 o;
  o.x = f2bf(v.x); o.y = f2bf(v.y); o.z = f2bf(v.z); o.w = f2bf(v.w);
  *(ushort4*)dst = o;
}

// Attention kernel, 2-wave-domain build: one block = (c, b, head-pair),
// 128 threads = 2 waves = 2 heads. Per-wave code BIT-IDENTICAL to R13 (each
// wave = one head, register-resident wk/wv slabs -- R8/R9 proved streaming
// 2.5-3x worse). Changes vs R13: grid 1216x256 -> 2432x128; 2 LDS x-buffers
// with 1 barrier/tile (R8/R9-verified rotation); 4 blocks/CU -> finer
// barrier-domain decorrelation (R1->R2's -53us mechanism, one step further).
__launch_bounds__(128, 2)
__global__ void attn_kernel(const float* __restrict__ b_in,
                            const unsigned short* __restrict__ xbf,
                            const unsigned short* __restrict__ wibf,
                            float* __restrict__ out) {
  // XCD-aware swizzle: same channel's tasks contiguous per XCD.
  const int bid = blockIdx.x;
  const int xcd = bid & 7;
  const int slot = bid >> 3;            // 0..303
  const int c = slot >> 4;              // 0..18
  const int p = ((slot & 15) << 3) | xcd;  // 0..127
  const int b = p >> 2;                 // 0..31
  const int hp = p & 3;                 // head pair 0..3

  const int tid = threadIdx.x;
  const int w = tid >> 6;               // wave 0..1
  const int lane = tid & 63;
  const int quad = lane >> 4;
  const int l16 = lane & 15;
  const int eh = (hp * 2 + w) * 32;     // this wave's head offset in e

  extern __shared__ char smem[];
  char* sx = smem;                              // 2 bufs x 16384 B
  unsigned* msk = (unsigned*)(smem + 32768);    // 32 q x 12 tiles
  float* sL = (float*)(smem + 34304);           // 2 waves x 32 floats

  const float scale = 0.25503486f;  // log2(e) / sqrt(32)
  const floatx4 fzero = {0.f, 0.f, 0.f, 0.f};

  // per-thread swizzle constants
  const int xw = (l16 & 7) << 4;         // read-side XOR (row = n4*16+l16)
  const size_t xrowbytes = (size_t)b * NPAD * 512;  // base of x[b] in bytes

  // ---- stage x tile 0 -> buf0 via global_load_lds (issue EARLY, Q-phase
  // hides the latency; prologue barrier drains vmcnt). 128 thr: 8 calls.
#pragma unroll
  for (int call = 0; call < 8; ++call) {
    const int sbyte = w * 8192 + call * 1024 + (lane << 4);
    const int row = sbyte >> 9;
    const int inner = (sbyte & 511) ^ ((row & 7) << 4);
    gload_lds16((const char*)xbf + xrowbytes + (size_t)row * 512 + inner,
                sx + w * 8192 + call * 1024);
  }

  // ---------------- Q phase: qf[mt][echunk] = B-frag of transposed scores.
  f16x4 qf[2][2];
  {
    bf16x8 wq[2][8];
#pragma unroll
    for (int m4 = 0; m4 < 2; ++m4)
#pragma unroll
      for (int k = 0; k < 8; ++k)
        wq[m4][k] = *(const bf16x8*)&wibf[(c * 768 + eh + m4 * 16 + l16) * DIM + k * 32 + quad * 8];
    float bq[2][4];
#pragma unroll
    for (int m4 = 0; m4 < 2; ++m4) {
      const float4 bv4 = *(const float4*)&b_in[c * 768 + eh + m4 * 16 + quad * 4];
      bq[m4][0] = bv4.x; bq[m4][1] = bv4.y; bq[m4][2] = bv4.z; bq[m4][3] = bv4.w;
    }
#pragma unroll
    for (int mt = 0; mt < 2; ++mt) {
      const int xrow = b * NPAD + c * CC + mt * 16 + l16;
      bf16x8 xq[8];
#pragma unroll
      for (int k = 0; k < 8; ++k)
        xq[k] = *(const bf16x8*)&xbf[xrow * DIM + k * 32 + quad * 8];
#pragma unroll
      for (int m4 = 0; m4 < 2; ++m4) {
        floatx4 acc = fzero;
#pragma unroll
        for (int k = 0; k < 8; ++k)
          acc = __builtin_amdgcn_mfma_f32_16x16x32_bf16(wq[m4][k], xq[k], acc, 0, 0, 0);
        qf[mt][m4] = pack4h((acc[0] + bq[m4][0]) * scale, (acc[1] + bq[m4][1]) * scale,
                            (acc[2] + bq[m4][2]) * scale, (acc[3] + bq[m4][3]) * scale);
      }
    }
  }

  // ---------------- head-local K/V weight slabs -> registers (loop-invariant)
  bf16x8 wk[2][8], wv[2][8];
#pragma unroll
  for (int m4 = 0; m4 < 2; ++m4)
#pragma unroll
    for (int k = 0; k < 8; ++k) {
      wk[m4][k] =
          *(const bf16x8*)&wibf[(c * 768 + 256 + eh + m4 * 16 + l16) * DIM + k * 32 + quad * 8];
      wv[m4][k] =
          *(const bf16x8*)&wibf[(c * 768 + 512 + eh + m4 * 16 + l16) * DIM + k * 32 + quad * 8];
    }
  // bk: dropped (softmax shift-invariance). bV folded to AO write.
  float bV[2];
#pragma unroll
  for (int ne = 0; ne < 2; ++ne) bV[ne] = b_in[c * 768 + 512 + eh + ne * 16 + l16];

  // ---------------- mask bitmask table: msk[q*12+t] bit i = key t*32+i allowed
  for (int e2 = tid; e2 < 384; e2 += 128) {
    const int q = e2 / 12;
    const int wd = e2 - q * 12;
    unsigned m = 0u;
    for (int i = 0; i < 32; ++i) {
      const int kabs = wd * 32 + i;
      const unsigned ki = ((unsigned)kabs * 110377u) >> 21;  // kabs/19, kabs<=383
      const unsigned kj = (unsigned)kabs - ki * 19u;
      if (kabs < NPOS && (ki == (unsigned)c || kj == (unsigned)c ||
                          ki == (unsigned)q || kj == (unsigned)q))
        m |= (1u << i);
    }
    msk[e2] = m;
  }

  floatx4 o_acc[2][2];
  float lsum[2] = {0.f, 0.f};
#pragma unroll
  for (int mt = 0; mt < 2; ++mt)
#pragma unroll
    for (int ne = 0; ne < 2; ++ne) o_acc[mt][ne] = fzero;

  __syncthreads();  // tile 0 DMA'd (vmcnt drained) + mask table built

  // ---- main loop: 12 tiles, double-buffered, one barrier per tile.
  // Iteration t stages t+1 into buf[(t+1)&1] (last read in iter t-1, freed by
  // that iteration's end barrier); end barrier makes staging visible for t+1.
  for (int t = 0; t < NTILES; ++t) {
    if (t + 1 < NTILES) {
      char* bxn = sx + ((t + 1) & 1) * 16384;
#pragma unroll
      for (int call = 0; call < 8; ++call) {
        const int sbyte = w * 8192 + call * 1024 + (lane << 4);
        const int row = sbyte >> 9;
        const int inner = (sbyte & 511) ^ ((row & 7) << 4);
        gload_lds16((const char*)xbf + xrowbytes + (size_t)((t + 1) * TKEY + row) * 512 + inner,
                    bxn + w * 8192 + call * 1024);
      }
    }
    const char* bx = sx + (t & 1) * 16384;

    // ---------------- K/V projection, all-register outputs
    floatx4 aK[2][2], aV[2][2];
#pragma unroll
    for (int i = 0; i < 2; ++i)
#pragma unroll
      for (int j = 0; j < 2; ++j) { aK[i][j] = fzero; aV[i][j] = fzero; }
    __builtin_amdgcn_s_setprio(1);
#pragma unroll
    for (int k = 0; k < 8; ++k) {
      bf16x8 xfr[2];
#pragma unroll
      for (int n4 = 0; n4 < 2; ++n4) {
        const int row = n4 * 16 + l16;
        const int inner = (k * 64 + quad * 16) ^ xw;
        xfr[n4] = *(const bf16x8*)(bx + row * 512 + inner);
      }
#pragma unroll
      for (int m4 = 0; m4 < 2; ++m4)
#pragma unroll
        for (int n4 = 0; n4 < 2; ++n4) {
          aK[m4][n4] = __builtin_amdgcn_mfma_f32_16x16x32_bf16(wk[m4][k], xfr[n4], aK[m4][n4], 0, 0, 0);
          aV[n4][m4] = __builtin_amdgcn_mfma_f32_16x16x32_bf16(xfr[n4], wv[m4][k], aV[n4][m4], 0, 0, 0);
        }
    }
    __builtin_amdgcn_s_setprio(0);

    // convert to MFMA-ready f16 fragments
    f16x4 kf[2][2];
    f16x4 vf[2][2];
#pragma unroll
    for (int kt = 0; kt < 2; ++kt)
#pragma unroll
      for (int ec = 0; ec < 2; ++ec) {
        kf[kt][ec] = pack4h(aK[ec][kt][0], aK[ec][kt][1], aK[ec][kt][2], aK[ec][kt][3]);
        vf[kt][ec] = pack4h(aV[kt][ec][0], aV[kt][ec][1], aV[kt][ec][2], aV[kt][ec][3]);
      }

    // ---------------- scores (transposed) + bitmask + exp2 + PV, in registers
#pragma unroll
    for (int mt = 0; mt < 2; ++mt) {
      const int q = mt * 16 + l16;
      const unsigned mw = msk[q * 12 + t];
      f16x4 pf[2];
#pragma unroll
      for (int kt = 0; kt < 2; ++kt) {
        floatx4 s2 = __builtin_amdgcn_mfma_f32_16x16x16f16(kf[kt][0], qf[mt][0], fzero, 0, 0, 0);
        s2 = __builtin_amdgcn_mfma_f32_16x16x16f16(kf[kt][1], qf[mt][1], s2, 0, 0, 0);
        const unsigned mk = mw >> (kt * 16 + quad * 4);
        float p2[4];
#pragma unroll
        for (int r = 0; r < 4; ++r)
          p2[r] = (mk & (1u << r)) ? __builtin_exp2f(s2[r]) : 0.f;
        lsum[mt] += (p2[0] + p2[1]) + (p2[2] + p2[3]);
        pf[kt] = pack4h(p2[0], p2[1], p2[2], p2[3]);
      }
      __builtin_amdgcn_s_setprio(1);
#pragma unroll
      for (int kt = 0; kt < 2; ++kt)
#pragma unroll
        for (int ne = 0; ne < 2; ++ne)
          o_acc[mt][ne] =
              __builtin_amdgcn_mfma_f32_16x16x16f16(pf[kt], vf[kt][ne], o_acc[mt][ne], 0, 0, 0);
      __builtin_amdgcn_s_setprio(0);
    }
    if (t + 1 < NTILES) __syncthreads();  // staging of t+1 visible; buf[t&1] freed
  }

  // ---------------- denom: reduce lsum across quads, publish per wave
#pragma unroll
  for (int mt = 0; mt < 2; ++mt) {
    lsum[mt] += __shfl_xor(lsum[mt], 16);
    lsum[mt] += __shfl_xor(lsum[mt], 32);
  }
  if (lane < 16) {
    sL[w * 32 + lane] = lsum[0];
    sL[w * 32 + 16 + lane] = lsum[1];
  }
  // wave-local LDS round-trip (lgkmcnt-ordered), no barrier needed
  float invl[2][4];
#pragma unroll
  for (int mt = 0; mt < 2; ++mt)
#pragma unroll
    for (int r = 0; r < 4; ++r)
      invl[mt][r] = 1.f / sL[w * 32 + mt * 16 + quad * 4 + r];

  // ---------------- AO (rows<19 only, +bV) -> front half of this (c,b)'s out region
  unsigned short* aop = (unsigned short*)(out + (size_t)(b * NPOS + c * CC) * DIM);
#pragma unroll
  for (int mt = 0; mt < 2; ++mt)
#pragma unroll
    for (int ne = 0; ne < 2; ++ne)
#pragma unroll
      for (int r = 0; r < 4; ++r) {
        const int q = mt * 16 + quad * 4 + r;
        if (q < CC)
          aop[q * DIM + eh + ne * 16 + l16] =
              f2bf(o_acc[mt][ne][r] * invl[mt][r] + bV[ne]);
      }
}

// Epilogue: per (c,b): AO (bf16, in out-region front half) -> LDS; GEMM1 with
// w_out^T + b_out -> LDS; GEMM2 with w_fuse^T + b_fuse + x -> out (f32, full
// overwrite of the region). 8 waves (512 thr). Separate launch REQUIRED:
// kernel boundary is the cross-XCD coherence point (R11/R12 fused-handoff
// attempts both produced wrong results; R14 in-block fusion net-negative).
__launch_bounds__(512)
__global__ void epi_kernel(const float* __restrict__ xf,
                           const float* __restrict__ b_out,
                           const float* __restrict__ b_fuse,
                           const unsigned short* __restrict__ wobf,
                           const unsigned short* __restrict__ wfbf,
                           float* __restrict__ out) {
  const int bid = blockIdx.x;
  const int xcd = bid & 7;
  const int slot = bid >> 3;          // 0..75
  const int c = slot >> 2;            // 0..18
  const int b = ((slot & 3) << 3) | xcd;

  const int tid = threadIdx.x;
  const int w = tid >> 6;             // 0..7
  const int lane = tid & 63;
  const int quad = lane >> 4;
  const int l16 = lane & 15;

  __shared__ unsigned short sA[32 * 264];
  __shared__ unsigned short sT[32 * 264];

  const size_t fbase = (size_t)(b * NPOS + c * CC) * DIM;
  const unsigned short* aop = (const unsigned short*)(out + fbase);
  const floatx4 fzero = {0.f, 0.f, 0.f, 0.f};
  const bf16x8 zero8 = {};

#pragma unroll
  for (int it = 0; it < 2; ++it) {
    const int cc2 = tid + it * 512;
    const int row = cc2 >> 5;
    const int col = (cc2 & 31) * 8;
    bf16x8 v = zero8;
    if (row < CC) v = *(const bf16x8*)&aop[row * DIM + col];
    *(bf16x8*)&sA[row * 264 + col] = v;
  }
  __syncthreads();

  // GEMM1: T = AO @ w_out^T + b_out
#pragma unroll
  for (int mt = 0; mt < 2; ++mt) {
    bf16x8 a8[8];
#pragma unroll
    for (int k = 0; k < 8; ++k)
      a8[k] = *(const bf16x8*)&sA[(mt * 16 + l16) * 264 + k * 32 + quad * 8];
#pragma unroll
    for (int nt2 = 0; nt2 < 2; ++nt2) {
      const int e0 = w * 32 + nt2 * 16;
      floatx4 acc = fzero;
#pragma unroll
      for (int k = 0; k < 8; ++k) {
        bf16x8 b8 = *(const bf16x8*)&wobf[(c * 256 + e0 + l16) * DIM + k * 32 + quad * 8];
        acc = __builtin_amdgcn_mfma_f32_16x16x32_bf16(a8[k], b8, acc, 0, 0, 0);
      }
      const float bias = b_out[c * 256 + e0 + l16];
#pragma unroll
      for (int r = 0; r < 4; ++r)
        sT[(mt * 16 + quad * 4 + r) * 264 + e0 + l16] = f2bf(acc[r] + bias);
    }
  }
  __syncthreads();

  // GEMM2: out = T @ w_fuse^T + b_fuse + x
#pragma unroll
  for (int mt = 0; mt < 2; ++mt) {
    bf16x8 a8[8];
#pragma unroll
    for (int k = 0; k < 8; ++k)
      a8[k] = *(const bf16x8*)&sT[(mt * 16 + l16) * 264 + k * 32 + quad * 8];
#pragma unroll
    for (int nt2 = 0; nt2 < 2; ++nt2) {
      const int e0 = w * 32 + nt2 * 16;
      floatx4 acc = fzero;
#pragma unroll
      for (int k = 0; k < 8; ++k) {
        bf16x8 b8 = *(const bf16x8*)&wfbf[(e0 + l16) * DIM + k * 32 + quad * 8];
        acc = __builtin_amdgcn_mfma_f32_16x16x32_bf16(a8[k], b8, acc, 0, 0, 0);
      }
      const float bfu = b_fuse[e0 + l16];
#pragma unroll
      for (int r = 0; r < 4; ++r) {
        const int row = mt * 16 + quad * 4 + r;
        if (row < CC) {
          const size_t gp = fbase + (size_t)row * DIM + e0 + l16;
          out[gp] = acc[r] + bfu + xf[gp];
        }
      }
    }
  }
}

extern "C" void kernel_launch(void* const* d_in, const int* in_sizes, int n_in,
                              void* d_out, int out_size, void* d_ws, size_t ws_size,
                              hipStream_t stream) {
  const float* x      = (const float*)d_in[0];
  const float* w_in   = (const float*)d_in[1];
  const float* b_in   = (const float*)d_in[2];
  const float* w_out  = (const float*)d_in[3];
  const float* b_out  = (const float*)d_in[4];
  const float* w_fuse = (const float*)d_in[5];
  const float* b_fuse = (const float*)d_in[6];
  float* out = (float*)d_out;

  if (ws_size < (size_t)16384000) return;  // 16.38 MB bf16 scratch (validated bound)

  unsigned short* ws = (unsigned short*)d_ws;
  unsigned short* x_bf  = ws;              // 32*384*256   = 3,145,728
  unsigned short* wi_bf = ws + 3145728;    // 19*768*256   = 3,735,552
  unsigned short* wo_bf = ws + 6881280;    // 19*256*256   = 1,245,184
  unsigned short* wf_bf = ws + 8126464;    // 256*256      = 65,536

  conv_all_kernel<<<8000, 256, 0, stream>>>(x, w_in, w_out, w_fuse, ws);

  (void)hipFuncSetAttribute((const void*)attn_kernel,
                            hipFuncAttributeMaxDynamicSharedMemorySize, LDS_BYTES);
  attn_kernel<<<2432, 128, LDS_BYTES, stream>>>(b_in, x_bf, wi_bf, out);

  epi_kernel<<<608, 512, 0, stream>>>(x, b_out, b_fuse, wo_bf, wf_bf, out);
}

// Round 17
// 232.741 us; speedup vs baseline: 1.0646x; 1.0646x over previous
//
#include <hip/hip_runtime.h>

#define CC 19
#define NPOS 361
#define NPAD 384
#define DIM 256
#define TKEY 32
#define NTILES 12

// attn LDS layout (bytes):
//   [0, 65536)      : 4 x-buffers, each 32 rows x 512 B (UNPADDED, XOR-swizzled
//                     via pre-swizzled global source; rotation t%4)
//   [65536, 67072)  : mask table 32 q x 12 tiles u32
//   [67072, 67584)  : sL (4 waves x 32 floats)
// 67584 x 2 blocks = 135168 <= 160 KiB -> 2 blocks/CU co-resident.
#define LDS_BYTES 67584

using bf16x8 = __attribute__((ext_vector_type(8))) short;
using f16x4  = __attribute__((ext_vector_type(4))) _Float16;
using floatx4 = __attribute__((ext_vector_type(4))) float;
using uintx2 = __attribute__((ext_vector_type(2))) unsigned int;

__device__ __forceinline__ unsigned short f2bf(float f) {
  unsigned u = __builtin_bit_cast(unsigned, f);
  u += 0x7fffu + ((u >> 16) & 1u);
  return (unsigned short)(u >> 16);
}

__device__ __forceinline__ f16x4 pack4h(float a, float b, float c2, float d) {
  const auto h01 = __builtin_amdgcn_cvt_pkrtz(a, b);
  const auto h23 = __builtin_amdgcn_cvt_pkrtz(c2, d);
  uintx2 uv = {__builtin_bit_cast(unsigned, h01), __builtin_bit_cast(unsigned, h23)};
  return __builtin_bit_cast(f16x4, uv);
}

// direct global->LDS DMA, 16 B per lane (HW: lds dest = wave-uniform base + lane*16)
__device__ __forceinline__ void gload_lds16(const void* g, void* l) {
  __builtin_amdgcn_global_load_lds(
      (const __attribute__((address_space(1))) void*)g,
      (__attribute__((address_space(3))) void*)l, 16, 0, 0);
}

// fused conversion: x (zero-padded 361->384 rows) + all weights, f32 -> bf16
__global__ void conv_all_kernel(const float* __restrict__ x,
                                const float* __restrict__ w_in,
                                const float* __restrict__ w_out,
                                const float* __restrict__ w_fuse,
                                unsigned short* __restrict__ ws) {
  const int j = blockIdx.x * 256 + threadIdx.x;
  float4 v = make_float4(0.f, 0.f, 0.f, 0.f);
  unsigned short* dst;
  if (j < 786432) {
    const int row = j >> 6;
    const int off = (j & 63) << 2;
    const int b = row / NPAD;
    const int r = row - b * NPAD;
    if (r < NPOS) v = *(const float4*)&x[(b * NPOS + r) * DIM + off];
    dst = &ws[row * DIM + off];
  } else if (j < 1720320) {
    const int k = j - 786432;
    v = *(const float4*)&w_in[k << 2];
    dst = &ws[3145728 + (k << 2)];
  } else if (j < 2031616) {
    const int k = j - 1720320;
    v = *(const float4*)&w_out[k << 2];
    dst = &ws[6881280 + (k << 2)];
  } else {
    const int k = j - 2031616;
    v = *(const float4*)&w_fuse[k << 2];
    dst = &ws[8126464 + (k << 2)];
  }
  ushort4 o;
  o.x = f2bf(v.x); o.y = f2bf(v.y); o.z = f2bf(v.z); o.w = f2bf(v.w);
  *(ushort4*)dst = o;
}

// Attention kernel -- FINAL, the measured optimum of this design space.
// One block = (c, b, head-half); 4 waves = 4 heads; two independent blocks
// per CU (separate barrier domains) decorrelate the two 256-reg waves/SIMD.
// Register-resident wk/wv slabs (~128 regs incl. AGPRs) pin 2 waves/SIMD --
// PROVEN CHEAPER than every alternative tried:
//   R4: cross-tile deferred softmax  -> liveset > 256, spills (WRITE 207 MB)
//   R8: stream weights, (256,3)      -> LICM rebuilt slabs, spills (138 MB)
//   R9: stream weights + LICM fence  -> clean, 32% occ, but per-k L2 latency
//       exposed: 307 us (3x WORSE).
//   R11/R12: fused epilogue via cross-XCD handoff -> WRONG RESULTS twice
//       (threadfence, then SYSTEM-scope atomics both insufficient for
//       cross-XCD producer->consumer visibility; Guideline 16 upheld).
//   R14: in-block fusion (512 thr, 8 waves) -> lockstep penalty 104->162 us.
//   R16: 2-wave domains (128 thr, 4 blk/CU) -> doubled barriers+prologues:
//       104->122 us. Decorrelation axis: 8w=162, 4w=104, 2w=122 -> interior
//       optimum IS this configuration.
// Staging via global_load_lds DMA; LDS unpadded + XOR swizzle (pre-swizzled
// global source, swizzled read); one barrier per 2 tiles.
__launch_bounds__(256, 2)
__global__ void attn_kernel(const float* __restrict__ b_in,
                            const unsigned short* __restrict__ xbf,
                            const unsigned short* __restrict__ wibf,
                            float* __restrict__ out) {
  // XCD-aware swizzle: same channel's tasks contiguous per XCD.
  const int bid = blockIdx.x;
  const int xcd = bid & 7;
  const int slot = bid >> 3;           // 0..151
  const int c = slot >> 3;             // 0..18
  const int p = ((slot & 7) << 3) | xcd;  // 0..63
  const int b = p >> 1;                // 0..31
  const int hb = p & 1;                // head half

  const int tid = threadIdx.x;
  const int w = tid >> 6;              // wave 0..3
  const int lane = tid & 63;
  const int quad = lane >> 4;
  const int l16 = lane & 15;
  const int eh = (hb * 4 + w) * 32;    // this wave's head offset in e

  extern __shared__ char smem[];
  char* sx = smem;                              // 4 bufs x 16384 B
  unsigned* msk = (unsigned*)(smem + 65536);    // 32 q x 12 tiles
  float* sL = (float*)(smem + 67072);           // 4 waves x 32 floats

  const float scale = 0.25503486f;  // log2(e) / sqrt(32)
  const floatx4 fzero = {0.f, 0.f, 0.f, 0.f};

  // per-thread swizzle constants
  const int xw = (l16 & 7) << 4;         // read-side XOR (row = n4*16+l16)
  const size_t xrowbytes = (size_t)b * NPAD * 512;  // base of x[b] in bytes

  // ---- stage x tiles 0,1 -> bufs 0,1 via global_load_lds (issue EARLY,
  // the Q-phase below hides the latency; barrier drains vmcnt).
#pragma unroll
  for (int u = 0; u < 2; ++u) {
#pragma unroll
    for (int call = 0; call < 4; ++call) {
      const int sbyte = w * 4096 + call * 1024 + (lane << 4);
      const int row = sbyte >> 9;
      const int inner = (sbyte & 511) ^ ((row & 7) << 4);
      gload_lds16((const char*)xbf + xrowbytes + (size_t)(u * TKEY + row) * 512 + inner,
                  sx + u * 16384 + w * 4096 + call * 1024);
    }
  }

  // ---------------- Q phase: qf[mt][echunk] = B-frag of transposed scores.
  f16x4 qf[2][2];
  {
    bf16x8 wq[2][8];
#pragma unroll
    for (int m4 = 0; m4 < 2; ++m4)
#pragma unroll
      for (int k = 0; k < 8; ++k)
        wq[m4][k] = *(const bf16x8*)&wibf[(c * 768 + eh + m4 * 16 + l16) * DIM + k * 32 + quad * 8];
    float bq[2][4];
#pragma unroll
    for (int m4 = 0; m4 < 2; ++m4) {
      const float4 bv4 = *(const float4*)&b_in[c * 768 + eh + m4 * 16 + quad * 4];
      bq[m4][0] = bv4.x; bq[m4][1] = bv4.y; bq[m4][2] = bv4.z; bq[m4][3] = bv4.w;
    }
#pragma unroll
    for (int mt = 0; mt < 2; ++mt) {
      const int xrow = b * NPAD + c * CC + mt * 16 + l16;
      bf16x8 xq[8];
#pragma unroll
      for (int k = 0; k < 8; ++k)
        xq[k] = *(const bf16x8*)&xbf[xrow * DIM + k * 32 + quad * 8];
#pragma unroll
      for (int m4 = 0; m4 < 2; ++m4) {
        floatx4 acc = fzero;
#pragma unroll
        for (int k = 0; k < 8; ++k)
          acc = __builtin_amdgcn_mfma_f32_16x16x32_bf16(wq[m4][k], xq[k], acc, 0, 0, 0);
        qf[mt][m4] = pack4h((acc[0] + bq[m4][0]) * scale, (acc[1] + bq[m4][1]) * scale,
                            (acc[2] + bq[m4][2]) * scale, (acc[3] + bq[m4][3]) * scale);
      }
    }
  }

  // ---------------- head-local K/V weight slabs -> registers (loop-invariant)
  bf16x8 wk[2][8], wv[2][8];
#pragma unroll
  for (int m4 = 0; m4 < 2; ++m4)
#pragma unroll
    for (int k = 0; k < 8; ++k) {
      wk[m4][k] =
          *(const bf16x8*)&wibf[(c * 768 + 256 + eh + m4 * 16 + l16) * DIM + k * 32 + quad * 8];
      wv[m4][k] =
          *(const bf16x8*)&wibf[(c * 768 + 512 + eh + m4 * 16 + l16) * DIM + k * 32 + quad * 8];
    }
  // bk: dropped (softmax shift-invariance). bV folded to AO write.
  float bV[2];
#pragma unroll
  for (int ne = 0; ne < 2; ++ne) bV[ne] = b_in[c * 768 + 512 + eh + ne * 16 + l16];

  // ---------------- mask bitmask table: msk[q*12+t] bit i = key t*32+i allowed
  for (int e2 = tid; e2 < 384; e2 += 256) {
    const int q = e2 / 12;
    const int wd = e2 - q * 12;
    unsigned m = 0u;
    for (int i = 0; i < 32; ++i) {
      const int kabs = wd * 32 + i;
      const unsigned ki = ((unsigned)kabs * 110377u) >> 21;  // kabs/19, kabs<=383
      const unsigned kj = (unsigned)kabs - ki * 19u;
      if (kabs < NPOS && (ki == (unsigned)c || kj == (unsigned)c ||
                          ki == (unsigned)q || kj == (unsigned)q))
        m |= (1u << i);
    }
    msk[e2] = m;
  }

  floatx4 o_acc[2][2];
  float lsum[2] = {0.f, 0.f};
#pragma unroll
  for (int mt = 0; mt < 2; ++mt)
#pragma unroll
    for (int ne = 0; ne < 2; ++ne) o_acc[mt][ne] = fzero;

  __syncthreads();  // tiles 0,1 DMA'd (vmcnt drained) + mask table built

  // ---- main loop: 6 super-iterations of 2 tiles; ONE barrier each (none last).
  for (int s6 = 0; s6 < 6; ++s6) {
    const int tb = s6 * 2;
    if (s6 < 5) {
#pragma unroll
      for (int u = 0; u < 2; ++u) {
        const int t = tb + 2 + u;
        char* bxn = sx + (t & 3) * 16384;
#pragma unroll
        for (int call = 0; call < 4; ++call) {
          const int sbyte = w * 4096 + call * 1024 + (lane << 4);
          const int row = sbyte >> 9;
          const int inner = (sbyte & 511) ^ ((row & 7) << 4);
          gload_lds16((const char*)xbf + xrowbytes + (size_t)(t * TKEY + row) * 512 + inner,
                      bxn + w * 4096 + call * 1024);
        }
      }
    }

#pragma unroll
    for (int u = 0; u < 2; ++u) {
      const int t = tb + u;
      const char* bx = sx + (t & 3) * 16384;

      // ---------------- K/V projection, all-register outputs
      floatx4 aK[2][2], aV[2][2];
#pragma unroll
      for (int i = 0; i < 2; ++i)
#pragma unroll
        for (int j = 0; j < 2; ++j) { aK[i][j] = fzero; aV[i][j] = fzero; }
      __builtin_amdgcn_s_setprio(1);
#pragma unroll
      for (int k = 0; k < 8; ++k) {
        bf16x8 xfr[2];
#pragma unroll
        for (int n4 = 0; n4 < 2; ++n4) {
          const int row = n4 * 16 + l16;
          const int inner = (k * 64 + quad * 16) ^ xw;
          xfr[n4] = *(const bf16x8*)(bx + row * 512 + inner);
        }
#pragma unroll
        for (int m4 = 0; m4 < 2; ++m4)
#pragma unroll
          for (int n4 = 0; n4 < 2; ++n4) {
            aK[m4][n4] = __builtin_amdgcn_mfma_f32_16x16x32_bf16(wk[m4][k], xfr[n4], aK[m4][n4], 0, 0, 0);
            aV[n4][m4] = __builtin_amdgcn_mfma_f32_16x16x32_bf16(xfr[n4], wv[m4][k], aV[n4][m4], 0, 0, 0);
          }
      }
      __builtin_amdgcn_s_setprio(0);

      // convert to MFMA-ready f16 fragments
      f16x4 kf[2][2];
      f16x4 vf[2][2];
#pragma unroll
      for (int kt = 0; kt < 2; ++kt)
#pragma unroll
        for (int ec = 0; ec < 2; ++ec) {
          kf[kt][ec] = pack4h(aK[ec][kt][0], aK[ec][kt][1], aK[ec][kt][2], aK[ec][kt][3]);
          vf[kt][ec] = pack4h(aV[kt][ec][0], aV[kt][ec][1], aV[kt][ec][2], aV[kt][ec][3]);
        }

      // ---------------- scores (transposed) + bitmask + exp2 + PV, in registers
#pragma unroll
      for (int mt = 0; mt < 2; ++mt) {
        const int q = mt * 16 + l16;
        const unsigned mw = msk[q * 12 + t];
        f16x4 pf[2];
#pragma unroll
        for (int kt = 0; kt < 2; ++kt) {
          floatx4 s2 = __builtin_amdgcn_mfma_f32_16x16x16f16(kf[kt][0], qf[mt][0], fzero, 0, 0, 0);
          s2 = __builtin_amdgcn_mfma_f32_16x16x16f16(kf[kt][1], qf[mt][1], s2, 0, 0, 0);
          const unsigned mk = mw >> (kt * 16 + quad * 4);
          float p[4];
#pragma unroll
          for (int r = 0; r < 4; ++r)
            p[r] = (mk & (1u << r)) ? __builtin_exp2f(s2[r]) : 0.f;
          lsum[mt] += (p[0] + p[1]) + (p[2] + p[3]);
          pf[kt] = pack4h(p[0], p[1], p[2], p[3]);
        }
        __builtin_amdgcn_s_setprio(1);
#pragma unroll
        for (int kt = 0; kt < 2; ++kt)
#pragma unroll
          for (int ne = 0; ne < 2; ++ne)
            o_acc[mt][ne] =
                __builtin_amdgcn_mfma_f32_16x16x16f16(pf[kt], vf[kt][ne], o_acc[mt][ne], 0, 0, 0);
        __builtin_amdgcn_s_setprio(0);
      }
    }
    if (s6 < 5) __syncthreads();  // staging DMA of tb+2/tb+3 done, reads of tb/tb+1 done
  }

  // ---------------- denom: reduce lsum across quads, publish per wave
#pragma unroll
  for (int mt = 0; mt < 2; ++mt) {
    lsum[mt] += __shfl_xor(lsum[mt], 16);
    lsum[mt] += __shfl_xor(lsum[mt], 32);
  }
  if (lane < 16) {
    sL[w * 32 + lane] = lsum[0];
    sL[w * 32 + 16 + lane] = lsum[1];
  }
  // wave-local LDS round-trip (lgkmcnt-ordered), no barrier needed
  float invl[2][4];
#pragma unroll
  for (int mt = 0; mt < 2; ++mt)
#pragma unroll
    for (int r = 0; r < 4; ++r)
      invl[mt][r] = 1.f / sL[w * 32 + mt * 16 + quad * 4 + r];

  // ---------------- AO (rows<19 only, +bV) -> front half of this (c,b)'s out region
  unsigned short* aop = (unsigned short*)(out + (size_t)(b * NPOS + c * CC) * DIM);
#pragma unroll
  for (int mt = 0; mt < 2; ++mt)
#pragma unroll
    for (int ne = 0; ne < 2; ++ne)
#pragma unroll
      for (int r = 0; r < 4; ++r) {
        const int q = mt * 16 + quad * 4 + r;
        if (q < CC)
          aop[q * DIM + eh + ne * 16 + l16] =
              f2bf(o_acc[mt][ne][r] * invl[mt][r] + bV[ne]);
      }
}

// Epilogue: per (c,b): AO (bf16, in out-region front half) -> LDS; GEMM1 with
// w_out^T + b_out -> LDS; GEMM2 with w_fuse^T + b_fuse + x -> out (f32, full
// overwrite of the region). 8 waves (512 thr): each wave owns 32 e-cols ->
// per-wave serial MFMA chain halved vs the 4-wave version, 19 waves/CU.
// Separate launch is REQUIRED: kernel boundary is the cross-XCD coherence
// point (R11/R12 fused-handoff attempts both produced wrong results; R14
// in-block fusion traded the launch for a bigger lockstep penalty).
__launch_bounds__(512)
__global__ void epi_kernel(const float* __restrict__ xf,
                           const float* __restrict__ b_out,
                           const float* __restrict__ b_fuse,
                           const unsigned short* __restrict__ wobf,
                           const unsigned short* __restrict__ wfbf,
                           float* __restrict__ out) {
  const int bid = blockIdx.x;
  const int xcd = bid & 7;
  const int slot = bid >> 3;          // 0..75
  const int c = slot >> 2;            // 0..18
  const int b = ((slot & 3) << 3) | xcd;

  const int tid = threadIdx.x;
  const int w = tid >> 6;             // 0..7
  const int lane = tid & 63;
  const int quad = lane >> 4;
  const int l16 = lane & 15;

  __shared__ unsigned short sA[32 * 264];
  __shared__ unsigned short sT[32 * 264];

  const size_t fbase = (size_t)(b * NPOS + c * CC) * DIM;
  const unsigned short* aop = (const unsigned short*)(out + fbase);
  const floatx4 fzero = {0.f, 0.f, 0.f, 0.f};
  const bf16x8 zero8 = {};

#pragma unroll
  for (int it = 0; it < 2; ++it) {
    const int cc2 = tid + it * 512;
    const int row = cc2 >> 5;
    const int col = (cc2 & 31) * 8;
    bf16x8 v = zero8;
    if (row < CC) v = *(const bf16x8*)&aop[row * DIM + col];
    *(bf16x8*)&sA[row * 264 + col] = v;
  }
  __syncthreads();

  // GEMM1: T = AO @ w_out^T + b_out
#pragma unroll
  for (int mt = 0; mt < 2; ++mt) {
    bf16x8 a8[8];
#pragma unroll
    for (int k = 0; k < 8; ++k)
      a8[k] = *(const bf16x8*)&sA[(mt * 16 + l16) * 264 + k * 32 + quad * 8];
#pragma unroll
    for (int nt2 = 0; nt2 < 2; ++nt2) {
      const int e0 = w * 32 + nt2 * 16;
      floatx4 acc = fzero;
#pragma unroll
      for (int k = 0; k < 8; ++k) {
        bf16x8 b8 = *(const bf16x8*)&wobf[(c * 256 + e0 + l16) * DIM + k * 32 + quad * 8];
        acc = __builtin_amdgcn_mfma_f32_16x16x32_bf16(a8[k], b8, acc, 0, 0, 0);
      }
      const float bias = b_out[c * 256 + e0 + l16];
#pragma unroll
      for (int r = 0; r < 4; ++r)
        sT[(mt * 16 + quad * 4 + r) * 264 + e0 + l16] = f2bf(acc[r] + bias);
    }
  }
  __syncthreads();

  // GEMM2: out = T @ w_fuse^T + b_fuse + x
#pragma unroll
  for (int mt = 0; mt < 2; ++mt) {
    bf16x8 a8[8];
#pragma unroll
    for (int k = 0; k < 8; ++k)
      a8[k] = *(const bf16x8*)&sT[(mt * 16 + l16) * 264 + k * 32 + quad * 8];
#pragma unroll
    for (int nt2 = 0; nt2 < 2; ++nt2) {
      const int e0 = w * 32 + nt2 * 16;
      floatx4 acc = fzero;
#pragma unroll
      for (int k = 0; k < 8; ++k) {
        bf16x8 b8 = *(const bf16x8*)&wfbf[(e0 + l16) * DIM + k * 32 + quad * 8];
        acc = __builtin_amdgcn_mfma_f32_16x16x32_bf16(a8[k], b8, acc, 0, 0, 0);
      }
      const float bfu = b_fuse[e0 + l16];
#pragma unroll
      for (int r = 0; r < 4; ++r) {
        const int row = mt * 16 + quad * 4 + r;
        if (row < CC) {
          const size_t gp = fbase + (size_t)row * DIM + e0 + l16;
          out[gp] = acc[r] + bfu + xf[gp];
        }
      }
    }
  }
}

extern "C" void kernel_launch(void* const* d_in, const int* in_sizes, int n_in,
                              void* d_out, int out_size, void* d_ws, size_t ws_size,
                              hipStream_t stream) {
  const float* x      = (const float*)d_in[0];
  const float* w_in   = (const float*)d_in[1];
  const float* b_in   = (const float*)d_in[2];
  const float* w_out  = (const float*)d_in[3];
  const float* b_out  = (const float*)d_in[4];
  const float* w_fuse = (const float*)d_in[5];
  const float* b_fuse = (const float*)d_in[6];
  float* out = (float*)d_out;

  if (ws_size < (size_t)16384000) return;  // 16.38 MB bf16 scratch (validated bound)

  unsigned short* ws = (unsigned short*)d_ws;
  unsigned short* x_bf  = ws;              // 32*384*256   = 3,145,728
  unsigned short* wi_bf = ws + 3145728;    // 19*768*256   = 3,735,552
  unsigned short* wo_bf = ws + 6881280;    // 19*256*256   = 1,245,184
  unsigned short* wf_bf = ws + 8126464;    // 256*256      = 65,536

  conv_all_kernel<<<8000, 256, 0, stream>>>(x, w_in, w_out, w_fuse, ws);

  (void)hipFuncSetAttribute((const void*)attn_kernel,
                            hipFuncAttributeMaxDynamicSharedMemorySize, LDS_BYTES);
  attn_kernel<<<1216, 256, LDS_BYTES, stream>>>(b_in, x_bf, wi_bf, out);

  epi_kernel<<<608, 512, 0, stream>>>(x, b_out, b_fuse, wo_bf, wf_bf, out);
}